// Round 2
// baseline (378.725 us; speedup 1.0000x reference)
//
#include <hip/hip_runtime.h>

#define N_NODES  500000
#define HIDDEN   256
#define N_GRAPHS 8192

typedef float f32x4 __attribute__((ext_vector_type(4)));
typedef short s16x8 __attribute__((ext_vector_type(8)));

__device__ __forceinline__ unsigned short f2bf(float f) {
    unsigned int u = __float_as_uint(f);
    u += 0x7fffu + ((u >> 16) & 1u);   // RNE round to bf16
    return (unsigned short)(u >> 16);
}

// Pack W1 [K=256][N=256] fp32 row-major into bf16 MFMA B-fragment order.
// For 16x16x32 bf16 MFMA: B[k][col], lane holds col = lane&15, k = (lane>>4)*8 + j.
// w1pack[ ((kt*16+nt)*64 + lane)*8 + j ] = bf16( W1[kt*32 + (lane>>4)*8 + j][nt*16 + (lane&15)] )
__global__ void prep_w1_kernel(const float* __restrict__ W1,
                               unsigned short* __restrict__ w1pack) {
    int tid  = blockIdx.x * 256 + threadIdx.x;   // 0..8191
    int lane = tid & 63;
    int tile = tid >> 6;                         // kt*16+nt, 0..127
    int kt = tile >> 4, nt = tile & 15;
    int krow = kt * 32 + ((lane >> 4) & 3) * 8;
    int col  = nt * 16 + (lane & 15);
    unsigned short tmp[8];
#pragma unroll
    for (int j = 0; j < 8; ++j)
        tmp[j] = f2bf(W1[(size_t)(krow + j) * 256 + col]);
    uint4* dst = (uint4*)(w1pack + (size_t)tid * 8);
    *dst = *(const uint4*)tmp;
}

__device__ __forceinline__ void flush_seg(float* __restrict__ num,
                                          float* __restrict__ den,
                                          int g, int lane, f32x4 v, float d) {
    float* dst = num + (size_t)g * HIDDEN + lane * 4;
    atomicAdd(dst + 0, v[0]);
    atomicAdd(dst + 1, v[1]);
    atomicAdd(dst + 2, v[2]);
    atomicAdd(dst + 3, v[3]);
    if (lane == 0) atomicAdd(den + g, d);
}

// Block: 256 threads = 4 waves, 64 nodes (16 per wave).
// LDS: x tile fp32 [64][256] XOR-swizzled (64 KiB) + W1 per-kt chunk (16 KiB).
__launch_bounds__(256, 2)
__global__ void attn_pool_main(const float* __restrict__ x,
                               const int*   __restrict__ batch,
                               const float* __restrict__ b1,
                               const float* __restrict__ W2,
                               const float* __restrict__ b2,
                               const unsigned short* __restrict__ w1pack,
                               float* __restrict__ num,
                               float* __restrict__ den) {
    __shared__ float xlds[64 * 256];              // 64 KiB
    __shared__ unsigned short w1buf[8192];        // 16 KiB

    const int tid  = threadIdx.x;
    const int wave = tid >> 6;
    const int lane = tid & 63;
    const int blockBase = blockIdx.x * 64;

    // ---- stage x tile, fp32, swizzle: unit(16B) index ^= (row&7) ----
#pragma unroll
    for (int i = 0; i < 16; ++i) {
        int u   = tid + i * 256;        // float4-unit id, 0..4095
        int row = u >> 6;
        int c4  = u & 63;
        f32x4 v = {0.f, 0.f, 0.f, 0.f};
        int grow = blockBase + row;
        if (grow < N_NODES)
            v = *(const f32x4*)(x + (size_t)grow * HIDDEN + (size_t)c4 * 4);
        int fidx = (row * 256) + ((c4 ^ (row & 7)) << 2);
        *(f32x4*)(xlds + fidx) = v;
    }

    // per-lane b1/W2 columns (col = nt*16 + (lane&15))
    const int cl = lane & 15;
    float b1c[16], w2c[16];
#pragma unroll
    for (int nt = 0; nt < 16; ++nt) {
        b1c[nt] = b1[nt * 16 + cl];
        w2c[nt] = W2[nt * 16 + cl];
    }
    const float b2v = b2[0];

    f32x4 acc[16];
#pragma unroll
    for (int i = 0; i < 16; ++i) acc[i] = (f32x4){0.f, 0.f, 0.f, 0.f};

    const int rowL = wave * 16 + cl;   // A-frag row (local)
    const int kgrp = lane >> 4;        // A-frag k-group

    for (int kt = 0; kt < 8; ++kt) {
        __syncthreads();               // protect w1buf readers / first: after x stage
        {
            const uint4* src = (const uint4*)(w1pack + (size_t)kt * 8192);
            uint4* dst = (uint4*)w1buf;
#pragma unroll
            for (int i = 0; i < 4; ++i)
                dst[tid + i * 256] = src[tid + i * 256];
        }
        __syncthreads();

        // A fragment: 8 fp32 from swizzled LDS -> bf16
        int c0u = kt * 8 + kgrp * 2;   // 16B-unit index of k-chunk start
        int u0 = (rowL * 256) + (((c0u    ) ^ (rowL & 7)) << 2);
        int u1 = (rowL * 256) + (((c0u + 1) ^ (rowL & 7)) << 2);
        f32x4 a0 = *(const f32x4*)(xlds + u0);
        f32x4 a1 = *(const f32x4*)(xlds + u1);
        s16x8 af;
        af[0] = (short)f2bf(a0[0]); af[1] = (short)f2bf(a0[1]);
        af[2] = (short)f2bf(a0[2]); af[3] = (short)f2bf(a0[3]);
        af[4] = (short)f2bf(a1[0]); af[5] = (short)f2bf(a1[1]);
        af[6] = (short)f2bf(a1[2]); af[7] = (short)f2bf(a1[3]);

#pragma unroll
        for (int nt = 0; nt < 16; ++nt) {
            s16x8 bfrag = *(const s16x8*)(w1buf + (size_t)(nt * 64 + lane) * 8);
            acc[nt] = __builtin_amdgcn_mfma_f32_16x16x32_bf16(af, bfrag, acc[nt], 0, 0, 0);
        }
    }

    // ---- h = tanh(acc + b1); partial logit = sum_cols h * w2 ----
    float sj[4] = {0.f, 0.f, 0.f, 0.f};
#pragma unroll
    for (int nt = 0; nt < 16; ++nt) {
#pragma unroll
        for (int j = 0; j < 4; ++j) {
            float h = acc[nt][j] + b1c[nt];
            h = fminf(fmaxf(h, -15.f), 15.f);
            float t  = __expf(2.f * h);
            float th = (t - 1.f) * __builtin_amdgcn_rcpf(t + 1.f);
            sj[j] += th * w2c[nt];
        }
    }
    // reduce across the 16 lanes of each row-group (lane>>4 fixed)
#pragma unroll
    for (int m = 1; m < 16; m <<= 1) {
#pragma unroll
        for (int j = 0; j < 4; ++j)
            sj[j] += __shfl_xor(sj[j], m, 64);
    }
    float ev[4];
#pragma unroll
    for (int j = 0; j < 4; ++j)
        ev[j] = __expf(sj[j] + b2v);   // e for row (lane>>4)*4 + j

    // ---- weighted segment accumulation (batch sorted) ----
    int tileBase = blockBase + wave * 16;
    if (tileBase < N_NODES) {          // tiles align: N % 16 == 0
        int bval = batch[tileBase + cl];
        f32x4 accv = {0.f, 0.f, 0.f, 0.f};
        float accden = 0.f;
        int gcur = __shfl(bval, 0, 64);
#pragma unroll
        for (int r = 0; r < 16; ++r) {
            int   g  = __shfl(bval, r, 64);
            float er = __shfl(ev[r & 3], (r >> 2) * 16, 64);
            if (g != gcur) {           // wave-uniform branch
                flush_seg(num, den, gcur, lane, accv, accden);
                accv = (f32x4){0.f, 0.f, 0.f, 0.f};
                accden = 0.f;
                gcur = g;
            }
            int rl = wave * 16 + r;
            int fidx = (rl * 256) + ((lane ^ (rl & 7)) << 2);
            f32x4 xv = *(const f32x4*)(xlds + fidx);
            accv += er * xv;
            accden += er;
        }
        flush_seg(num, den, gcur, lane, accv, accden);
    }
}

__global__ void finalize_kernel(float* __restrict__ out,
                                const float* __restrict__ den) {
    int i = blockIdx.x * 256 + threadIdx.x;      // 0..2M-1
    out[i] = out[i] / (den[i >> 8] + 1e-8f);
}

extern "C" void kernel_launch(void* const* d_in, const int* in_sizes, int n_in,
                              void* d_out, int out_size, void* d_ws, size_t ws_size,
                              hipStream_t stream) {
    const float* x     = (const float*)d_in[0];
    const int*   batch = (const int*)d_in[1];
    const float* W1    = (const float*)d_in[2];
    const float* b1    = (const float*)d_in[3];
    const float* W2    = (const float*)d_in[4];
    const float* b2    = (const float*)d_in[5];
    float* out = (float*)d_out;

    unsigned short* w1pack = (unsigned short*)d_ws;              // 128 KiB
    float* den = (float*)((char*)d_ws + 131072);                 // 32 KiB

    hipMemsetAsync(d_out, 0, (size_t)N_GRAPHS * HIDDEN * sizeof(float), stream);
    hipMemsetAsync(den, 0, (size_t)N_GRAPHS * sizeof(float), stream);

    prep_w1_kernel<<<32, 256, 0, stream>>>(W1, w1pack);

    int nblocks = (N_NODES + 63) / 64;   // 7813
    attn_pool_main<<<nblocks, 256, 0, stream>>>(x, batch, b1, W2, b2, w1pack, out, den);

    finalize_kernel<<<(N_GRAPHS * HIDDEN) / 256, 256, 0, stream>>>(out, den);
}